// Round 13
// baseline (133.844 us; speedup 1.0000x reference)
//
#include <hip/hip_runtime.h>
#include <algorithm>
#include <cstdint>

// PRNG: partitionable threefry, 32-bit combine = o0 ^ o1  [VERIFIED R4: absmax=0]
// Ledger: R8 gl2lds NEUTRAL; R9 fused-map -9us (device fence); R11 occupancy
// NEUTRAL; R12 T14 split NEUTRAL (TLP already hides latency).
// R13: colsum WITHOUT LDS — fixed f4-slot->column mapping per 2-row window
// (1380 = 2x690 floats = 345 f4) lets each thread accumulate its own columns
// in f64 REGISTERS from coalesced loads. No barriers, no ds traffic.

constexpr int W_ = 690;
constexpr int NSEG_ = 2 * W_ + 1;   // 1381 segments
constexpr int NCUTS_ = 2 * W_ + 2;  // 1382 cut points
constexpr int GR_ = 2;              // rows per window/tile
constexpr int GFLT_ = GR_ * W_;     // 1380 floats = 5520 B (16B-aligned)
constexpr int GF4_ = GFLT_ / 4;     // 345 float4

typedef float v4f_ __attribute__((ext_vector_type(4)));
typedef unsigned short v4u16_ __attribute__((ext_vector_type(4)));

struct PermArg { unsigned short p[NSEG_]; }; // 2762 B kernarg, values < 1381

// ---------------- host-side threefry2x32 (exact JAX semantics) ----------------
static inline uint32_t rotl32_(uint32_t x, int d) { return (x << d) | (x >> (32 - d)); }

static void tf2x32(uint32_t k0, uint32_t k1, uint32_t x0, uint32_t x1,
                   uint32_t& o0, uint32_t& o1) {
  const uint32_t ks2 = k0 ^ k1 ^ 0x1BD11BDAu;
  x0 += k0; x1 += k1;
  const int RA[4] = {13, 15, 26, 6}, RB[4] = {17, 29, 16, 24};
#define FOUR_(R) for (int i_ = 0; i_ < 4; ++i_) { x0 += x1; x1 = rotl32_(x1, R[i_]); x1 ^= x0; }
  FOUR_(RA) x0 += k1;  x1 += ks2 + 1u;
  FOUR_(RB) x0 += ks2; x1 += k0 + 2u;
  FOUR_(RA) x0 += k0;  x1 += k1 + 3u;
  FOUR_(RB) x0 += k1;  x1 += ks2 + 4u;
  FOUR_(RA) x0 += ks2; x1 += k0 + 5u;
#undef FOUR_
  o0 = x0; o1 = x1;
}

// perm = argsort(uniform(key(42), (1381,))) — pure function of constants.
static void compute_perm(unsigned short* perm) {
  uint32_t uk[NSEG_];
  for (int i = 0; i < NSEG_; ++i) {
    uint32_t o0, o1;
    tf2x32(0u, 42u, 0u, (uint32_t)i, o0, o1); // u64 count i: hi=0 -> x0, lo=i -> x1
    uk[i] = (o0 ^ o1) >> 9; // partitionable bit_width==32: bits1 ^ bits2
  }
  int idx[NSEG_];
  for (int i = 0; i < NSEG_; ++i) idx[i] = i;
  std::stable_sort(idx, idx + NSEG_, [&](int a, int b) { return uk[a] < uk[b]; });
  for (int k = 0; k < NSEG_; ++k) perm[k] = (unsigned short)idx[k];
}

// ---------------- pass 1: register-accumulating colsum (no LDS, no barriers) ----------------
// partial layout: [nblk][1380] f64 slot-sums (slot s covers column s%690),
// then [690] f64 tail-row sums (block 0; zero when rows even).
__global__ __launch_bounds__(256) void k_colsum(const float* __restrict__ img,
                                                double* __restrict__ partial,
                                                int nwin, int rows) {
  const int t = threadIdx.x;
  const bool h2 = (t < GF4_ - 256); // t < 89 owns a second quad
  double a0[4] = {0.0, 0.0, 0.0, 0.0};
  double a1[4] = {0.0, 0.0, 0.0, 0.0};
  for (int w = blockIdx.x; w < nwin; w += gridDim.x) {
    const v4f_* b4 = (const v4f_*)(img + (size_t)w * GFLT_); // 5520B*w: 16B aligned
    const v4f_ v0 = b4[t]; // coalesced: lane t -> 16B at t
#pragma unroll
    for (int e = 0; e < 4; ++e) a0[e] += (double)v0[e];
    if (h2) {
      const v4f_ v1 = b4[t + 256];
#pragma unroll
      for (int e = 0; e < 4; ++e) a1[e] += (double)v1[e];
    }
  }
  double* o = partial + (size_t)blockIdx.x * GFLT_;
#pragma unroll
  for (int e = 0; e < 4; ++e) o[4 * t + e] = a0[e];
  if (h2) {
#pragma unroll
    for (int e = 0; e < 4; ++e) o[4 * (t + 256) + e] = a1[e];
  }
  // tail row (rows odd): block 0 writes per-column sums (zeros when none)
  if (blockIdx.x == 0) {
    double* ex = partial + (size_t)gridDim.x * GFLT_;
    const int r0 = nwin * GR_;
    for (int p = t; p < W_; p += 256) {
      double s = 0.0;
      for (int r = r0; r < rows; ++r) s += (double)img[(size_t)r * W_ + p];
      ex[p] = s;
    }
  }
}

// ---------------- pass 1b: fixed-order reduction of slot partials ----------------
__global__ __launch_bounds__(64) void k_colreduce(const double* __restrict__ partial,
                                                  double* __restrict__ col, int nblk) {
  const int w = blockIdx.x;       // 690 blocks
  const int lane = threadIdx.x;   // one wave
  double s = 0.0;
  for (int b = lane; b < nblk; b += 64) {
    const double* pb = partial + (size_t)b * GFLT_;
    s += pb[w] + pb[w + W_];      // the 2 slots covering column w, fixed order
  }
  for (int off = 32; off >= 1; off >>= 1) s += __shfl_down(s, off);
  if (lane == 0) col[w] = s + partial[(size_t)nblk * GFLT_ + w]; // + tail row
}

// ---------------- hierarchical inclusive scan: 2 barriers, deterministic ----------------
template <int N>
__device__ inline void scan_fast(double* sa, int t, double* wtmp) {
  constexpr int C = (N + 255) / 256;
  double loc[C];
  const int base = t * C;
  double run = 0.0;
#pragma unroll
  for (int j = 0; j < C; ++j) {
    const int i = base + j;
    const double v = (i < N) ? sa[i] : 0.0;
    run += v;
    loc[j] = run;
  }
  const int lane = t & 63, wid = t >> 6;
  double x = run;
#pragma unroll
  for (int off = 1; off < 64; off <<= 1) {
    const double y = __shfl_up(x, off);
    if (lane >= off) x += y;
  }
  if (lane == 63) wtmp[wid] = x;
  __syncthreads(); // all sa reads done; wave totals visible
  double excl = x - run;
  for (int k = 0; k < wid; ++k) excl += wtmp[k];
#pragma unroll
  for (int j = 0; j < C; ++j) {
    const int i = base + j;
    if (i < N) sa[i] = excl + loc[j];
  }
  __syncthreads();
}

// ---------------- pass 2: the whole W=690 mapping pipeline, one block ----------------
__global__ __launch_bounds__(256) void k_map(const double* __restrict__ col,
                                             int* __restrict__ src, PermArg perm) {
  __shared__ double sa[NCUTS_];
  __shared__ double wtmp[4];
  __shared__ float ex[W_ + 1];
  __shared__ unsigned char mm[W_];
  __shared__ int hist[W_ + 1];
  __shared__ int cuts[NCUTS_];
  __shared__ int pl[NSEG_], cum[NSEG_], ssrc[W_];
  const int t = threadIdx.x;

  // 1) prefix sums of col (f64 scan; cast to f32 like reference cs)
  for (int i = t; i < W_; i += 256) sa[i] = col[i];
  __syncthreads();
  scan_fast<W_>(sa, t, wtmp);
  for (int i = t; i <= W_; i += 256) ex[i] = (i == 0) ? 0.0f : (float)sa[i - 1];
  __syncthreads();

  // 2) windowed mean >= global mean mask
  const float gmean = ex[W_] / 45219840.0f; // n_bc*W = 65536*690
  for (int w = t; w < W_; w += 256) {
    int e = (w + 4 < W_) ? w + 4 : W_;
    float wsum = ex[e] - ex[w];
    float wmean = wsum / ((float)(e - w) * 65536.0f);
    mm[w] = (wmean >= gmean) ? 1 : 0;
  }
  for (int i = t; i <= W_; i += 256) hist[i] = 0;
  __syncthreads();

  // 3) counting-sort histogram of cut values
  for (int w = t; w < W_; w += 256) {
    bool cur = mm[w] != 0;
    bool prv = (w > 0) && (mm[w - 1] != 0);
    bool nxt = (w < W_ - 1) && (mm[w + 1] != 0);
    int sv = (cur && !prv) ? w : W_;
    int lv = (cur && !nxt) ? w : W_;
    atomicAdd(&hist[sv], 1);
    atomicAdd(&hist[lv], 1);
  }
  if (t == 0) { atomicAdd(&hist[0], 1); atomicAdd(&hist[W_], 1); }
  __syncthreads();

  // 4) inclusive scan of histogram
  for (int i = t; i <= W_; i += 256) sa[i] = (double)hist[i];
  __syncthreads();
  scan_fast<W_ + 1>(sa, t, wtmp);
  for (int i = t; i <= W_; i += 256) hist[i] = (int)(sa[i] + 0.5);
  __syncthreads();

  // 5) sorted cuts: cuts[k] = min v with hist_incl[v] > k
  for (int k = t; k < NCUTS_; k += 256) {
    int lo = 0, hi = W_;
    while (lo < hi) { int mid = (lo + hi) >> 1; if (hist[mid] > k) hi = mid; else lo = mid + 1; }
    cuts[k] = lo;
  }
  __syncthreads();

  // 6) permuted lengths + cumulative sum
  for (int k = t; k < NSEG_; k += 256) { int p = perm.p[k]; pl[k] = cuts[p + 1] - cuts[p]; }
  __syncthreads();
  for (int k = t; k < NSEG_; k += 256) sa[k] = (double)pl[k];
  __syncthreads();
  scan_fast<NSEG_>(sa, t, wtmp);
  for (int k = t; k < NSEG_; k += 256) cum[k] = (int)(sa[k] + 0.5);
  __syncthreads();

  // 7) fill src
  for (int k = t; k < NSEG_; k += 256) {
    int L = pl[k];
    if (L > 0) {
      int base = cum[k] - L;
      int s0 = cuts[perm.p[k]];
      for (int j = 0; j < L; ++j) ssrc[base + j] = s0 + j;
    }
  }
  __syncthreads();
  for (int p = t; p < W_; p += 256) src[p] = ssrc[p];
}

// ---------------- pass 3: gather (unchanged from R12) ----------------
__global__ __launch_bounds__(256) void k_gather(const float* __restrict__ img,
                                                float* __restrict__ out,
                                                const int* __restrict__ src,
                                                int ntile, int rows) {
  __shared__ float buf[2][GFLT_];                   // 2 x 5520 B
  __shared__ __align__(8) unsigned short ss[GFLT_]; // 1380 x u16 row-resolved idx
  const int t = threadIdx.x;
  const bool h2 = (t + 256 < GF4_); // t < 89
  for (int i = t; i < W_; i += 256) {
    int s = src[i];
    ss[i] = (unsigned short)s;
    ss[i + W_] = (unsigned short)(s + W_);
  }
  v4f_ r0{}, r1{};

  auto load_tile = [&](int g) { // global -> regs, issued early
    const v4f_* in4 = (const v4f_*)(img + (size_t)g * GFLT_); // 5520B*g: 16B aligned
    r0 = in4[t];
    if (h2) r1 = in4[t + 256];
  };
  auto write_tile = [&](float* bp) { // regs -> LDS, late
    v4f_* t4 = (v4f_*)bp;
    t4[t] = r0;
    if (h2) t4[t + 256] = r1;
  };

  int g = blockIdx.x, phase = 0;
  if (g < ntile) { load_tile(g); write_tile(buf[0]); } // prologue stall (once)
  for (; g < ntile; g += gridDim.x) {
    __syncthreads(); // buf[phase] staged; prior reads of buf[phase^1] done
    const int gn = g + gridDim.x;
    if (gn < ntile) load_tile(gn); // loads in flight across the scatter phase
    const float* bp = buf[phase];
    v4f_* o4 = (v4f_*)(out + (size_t)g * GFLT_);
    {
      const v4u16_ iv = *(const v4u16_*)&ss[4 * t]; // one ds_read_b64
      v4f_ v;
      v[0] = bp[iv[0]];
      v[1] = bp[iv[1]];
      v[2] = bp[iv[2]];
      v[3] = bp[iv[3]];
      __builtin_nontemporal_store(v, &o4[t]);
    }
    if (h2) {
      const v4u16_ iv = *(const v4u16_*)&ss[4 * (t + 256)];
      v4f_ v;
      v[0] = bp[iv[0]];
      v[1] = bp[iv[1]];
      v[2] = bp[iv[2]];
      v[3] = bp[iv[3]];
      __builtin_nontemporal_store(v, &o4[t + 256]);
    }
    if (gn < ntile) write_tile(buf[phase ^ 1]); // write late, after scatter
    phase ^= 1;
  }
  // tail row (rows odd) — not hit for rows=65536
  const int tail0 = ntile * GR_;
  if (tail0 < rows && blockIdx.x == 0) {
    __syncthreads();
    for (int r = tail0; r < rows; ++r) {
      const float* in = img + (size_t)r * W_;
      float* o = out + (size_t)r * W_;
      for (int p = t; p < W_; p += 256) o[p] = in[ss[p]];
    }
  }
}

extern "C" void kernel_launch(void* const* d_in, const int* in_sizes, int n_in,
                              void* d_out, int out_size, void* d_ws, size_t ws_size,
                              hipStream_t stream) {
  const float* img = (const float*)d_in[0];
  float* out = (float*)d_out;
  const int rows = in_sizes[0] / W_; // 32*2048 = 65536

  // ws layout: col f64[690] @0 | src i32[690] @5632 | partial @8704:
  //   [nblk][1380] f64 + [690] f64 tail
  char* ws = (char*)d_ws;
  double* col = (double*)ws;
  int* src = (int*)(ws + 5632);
  double* partial = (double*)(ws + 8704);
  size_t avail = (ws_size > 8704 + 5520) ? ws_size - 8704 - 5520 : 0;
  int nblk = (int)std::min<size_t>(2048, avail / (GFLT_ * sizeof(double)));
  if (nblk < 1) nblk = 1;
  const int nwin = rows / GR_;      // full 2-row windows (tail handled in-kernel)
  const int ntile_g = rows / GR_;

  PermArg pa;
  compute_perm(pa.p); // host, input-independent, deterministic

  k_colsum<<<nblk, 256, 0, stream>>>(img, partial, nwin, rows);
  k_colreduce<<<W_, 64, 0, stream>>>(partial, col, nblk);
  k_map<<<1, 256, 0, stream>>>(col, src, pa);
  k_gather<<<2048, 256, 0, stream>>>(img, out, src, ntile_g, rows);
}

// Round 14
// 132.028 us; speedup vs baseline: 1.0138x; 1.0138x over previous
//
#include <hip/hip_runtime.h>
#include <algorithm>
#include <cstdint>

// PRNG: partitionable threefry, 32-bit combine = o0 ^ o1  [VERIFIED R4: absmax=0]
// Ledger: R8 gl2lds NEUTRAL; R9 fused-map -9us (device fence); R11 occupancy
// NEUTRAL; R12 T14 split NEUTRAL; R13 reg-accum colsum -18us REGRESSION
// (1 load in flight -> latency-serialized). R14: reg-accum colsum with
// 4-window unroll (8x16B loads in flight), gather reverted to R10 best.

constexpr int W_ = 690;
constexpr int NSEG_ = 2 * W_ + 1;   // 1381 segments
constexpr int NCUTS_ = 2 * W_ + 2;  // 1382 cut points
constexpr int GR_ = 2;              // rows per colsum window
constexpr int GFLT_ = GR_ * W_;     // 1380 floats = 5520 B (16B-aligned)
constexpr int GF4_ = GFLT_ / 4;     // 345 float4 per window
constexpr int TR4_ = 4;             // rows per gather tile
constexpr int TFLT_ = TR4_ * W_;    // 2760 floats = 11040 B
constexpr int TF4_ = TFLT_ / 4;     // 690 float4 per gather tile

typedef float v4f_ __attribute__((ext_vector_type(4)));
typedef int v4i_ __attribute__((ext_vector_type(4)));

struct PermArg { unsigned short p[NSEG_]; }; // 2762 B kernarg, values < 1381

// ---------------- host-side threefry2x32 (exact JAX semantics) ----------------
static inline uint32_t rotl32_(uint32_t x, int d) { return (x << d) | (x >> (32 - d)); }

static void tf2x32(uint32_t k0, uint32_t k1, uint32_t x0, uint32_t x1,
                   uint32_t& o0, uint32_t& o1) {
  const uint32_t ks2 = k0 ^ k1 ^ 0x1BD11BDAu;
  x0 += k0; x1 += k1;
  const int RA[4] = {13, 15, 26, 6}, RB[4] = {17, 29, 16, 24};
#define FOUR_(R) for (int i_ = 0; i_ < 4; ++i_) { x0 += x1; x1 = rotl32_(x1, R[i_]); x1 ^= x0; }
  FOUR_(RA) x0 += k1;  x1 += ks2 + 1u;
  FOUR_(RB) x0 += ks2; x1 += k0 + 2u;
  FOUR_(RA) x0 += k0;  x1 += k1 + 3u;
  FOUR_(RB) x0 += k1;  x1 += ks2 + 4u;
  FOUR_(RA) x0 += ks2; x1 += k0 + 5u;
#undef FOUR_
  o0 = x0; o1 = x1;
}

// perm = argsort(uniform(key(42), (1381,))) — pure function of constants.
static void compute_perm(unsigned short* perm) {
  uint32_t uk[NSEG_];
  for (int i = 0; i < NSEG_; ++i) {
    uint32_t o0, o1;
    tf2x32(0u, 42u, 0u, (uint32_t)i, o0, o1); // u64 count i: hi=0 -> x0, lo=i -> x1
    uk[i] = (o0 ^ o1) >> 9; // partitionable bit_width==32: bits1 ^ bits2
  }
  int idx[NSEG_];
  for (int i = 0; i < NSEG_; ++i) idx[i] = i;
  std::stable_sort(idx, idx + NSEG_, [&](int a, int b) { return uk[a] < uk[b]; });
  for (int k = 0; k < NSEG_; ++k) perm[k] = (unsigned short)idx[k];
}

// ---------------- pass 1: reg-accum colsum, 4-window unroll (no LDS) ----------------
// partial layout: [nblk][1380] f64 slot-sums (slot s covers column s%690),
// then [690] f64 tail-row sums (block 0; zeros when rows even).
__global__ __launch_bounds__(256) void k_colsum(const float* __restrict__ img,
                                                double* __restrict__ partial,
                                                int nwin, int rows) {
  const int t = threadIdx.x;
  const bool h2 = (t < GF4_ - 256); // t < 89 owns a second quad
  const int G = gridDim.x;
  double a0[4] = {0.0, 0.0, 0.0, 0.0};
  double a1[4] = {0.0, 0.0, 0.0, 0.0};

  int w = blockIdx.x;
  // main: 4 windows per step -> 8 x 16B loads in flight before any accumulate
  for (; w + 3 * G < nwin; w += 4 * G) {
    v4f_ q0_0, q0_1, q0_2, q0_3, q1_0{}, q1_1{}, q1_2{}, q1_3{};
    {
      const v4f_* b0 = (const v4f_*)(img + (size_t)(w + 0 * G) * GFLT_);
      const v4f_* b1 = (const v4f_*)(img + (size_t)(w + 1 * G) * GFLT_);
      const v4f_* b2 = (const v4f_*)(img + (size_t)(w + 2 * G) * GFLT_);
      const v4f_* b3 = (const v4f_*)(img + (size_t)(w + 3 * G) * GFLT_);
      q0_0 = b0[t]; q0_1 = b1[t]; q0_2 = b2[t]; q0_3 = b3[t];
      if (h2) { q1_0 = b0[t + 256]; q1_1 = b1[t + 256]; q1_2 = b2[t + 256]; q1_3 = b3[t + 256]; }
    }
#pragma unroll
    for (int e = 0; e < 4; ++e) {
      a0[e] += (double)q0_0[e] + (double)q0_1[e] + (double)q0_2[e] + (double)q0_3[e];
      a1[e] += (double)q1_0[e] + (double)q1_1[e] + (double)q1_2[e] + (double)q1_3[e];
    }
  }
  // remainder windows
  for (; w < nwin; w += G) {
    const v4f_* b4 = (const v4f_*)(img + (size_t)w * GFLT_);
    const v4f_ v0 = b4[t];
#pragma unroll
    for (int e = 0; e < 4; ++e) a0[e] += (double)v0[e];
    if (h2) {
      const v4f_ v1 = b4[t + 256];
#pragma unroll
      for (int e = 0; e < 4; ++e) a1[e] += (double)v1[e];
    }
  }
  double* o = partial + (size_t)blockIdx.x * GFLT_;
#pragma unroll
  for (int e = 0; e < 4; ++e) o[4 * t + e] = a0[e];
  if (h2) {
#pragma unroll
    for (int e = 0; e < 4; ++e) o[4 * (t + 256) + e] = a1[e];
  }
  // tail row (rows odd): block 0 writes per-column sums (zeros when none)
  if (blockIdx.x == 0) {
    double* ex = partial + (size_t)gridDim.x * GFLT_;
    const int r0 = nwin * GR_;
    for (int p = t; p < W_; p += 256) {
      double s = 0.0;
      for (int r = r0; r < rows; ++r) s += (double)img[(size_t)r * W_ + p];
      ex[p] = s;
    }
  }
}

// ---------------- pass 1b: fixed-order reduction of slot partials ----------------
__global__ __launch_bounds__(64) void k_colreduce(const double* __restrict__ partial,
                                                  double* __restrict__ col, int nblk) {
  const int w = blockIdx.x;       // 690 blocks
  const int lane = threadIdx.x;   // one wave
  double s = 0.0;
  for (int b = lane; b < nblk; b += 64) {
    const double* pb = partial + (size_t)b * GFLT_;
    s += pb[w] + pb[w + W_];      // the 2 slots covering column w, fixed order
  }
  for (int off = 32; off >= 1; off >>= 1) s += __shfl_down(s, off);
  if (lane == 0) col[w] = s + partial[(size_t)nblk * GFLT_ + w]; // + tail row
}

// ---------------- hierarchical inclusive scan: 2 barriers, deterministic ----------------
template <int N>
__device__ inline void scan_fast(double* sa, int t, double* wtmp) {
  constexpr int C = (N + 255) / 256;
  double loc[C];
  const int base = t * C;
  double run = 0.0;
#pragma unroll
  for (int j = 0; j < C; ++j) {
    const int i = base + j;
    const double v = (i < N) ? sa[i] : 0.0;
    run += v;
    loc[j] = run;
  }
  const int lane = t & 63, wid = t >> 6;
  double x = run;
#pragma unroll
  for (int off = 1; off < 64; off <<= 1) {
    const double y = __shfl_up(x, off);
    if (lane >= off) x += y;
  }
  if (lane == 63) wtmp[wid] = x;
  __syncthreads(); // all sa reads done; wave totals visible
  double excl = x - run;
  for (int k = 0; k < wid; ++k) excl += wtmp[k];
#pragma unroll
  for (int j = 0; j < C; ++j) {
    const int i = base + j;
    if (i < N) sa[i] = excl + loc[j];
  }
  __syncthreads();
}

// ---------------- pass 2: the whole W=690 mapping pipeline, one block ----------------
__global__ __launch_bounds__(256) void k_map(const double* __restrict__ col,
                                             int* __restrict__ src, PermArg perm) {
  __shared__ double sa[NCUTS_];
  __shared__ double wtmp[4];
  __shared__ float ex[W_ + 1];
  __shared__ unsigned char mm[W_];
  __shared__ int hist[W_ + 1];
  __shared__ int cuts[NCUTS_];
  __shared__ int pl[NSEG_], cum[NSEG_], ssrc[W_];
  const int t = threadIdx.x;

  // 1) prefix sums of col (f64 scan; cast to f32 like reference cs)
  for (int i = t; i < W_; i += 256) sa[i] = col[i];
  __syncthreads();
  scan_fast<W_>(sa, t, wtmp);
  for (int i = t; i <= W_; i += 256) ex[i] = (i == 0) ? 0.0f : (float)sa[i - 1];
  __syncthreads();

  // 2) windowed mean >= global mean mask
  const float gmean = ex[W_] / 45219840.0f; // n_bc*W = 65536*690
  for (int w = t; w < W_; w += 256) {
    int e = (w + 4 < W_) ? w + 4 : W_;
    float wsum = ex[e] - ex[w];
    float wmean = wsum / ((float)(e - w) * 65536.0f);
    mm[w] = (wmean >= gmean) ? 1 : 0;
  }
  for (int i = t; i <= W_; i += 256) hist[i] = 0;
  __syncthreads();

  // 3) counting-sort histogram of cut values
  for (int w = t; w < W_; w += 256) {
    bool cur = mm[w] != 0;
    bool prv = (w > 0) && (mm[w - 1] != 0);
    bool nxt = (w < W_ - 1) && (mm[w + 1] != 0);
    int sv = (cur && !prv) ? w : W_;
    int lv = (cur && !nxt) ? w : W_;
    atomicAdd(&hist[sv], 1);
    atomicAdd(&hist[lv], 1);
  }
  if (t == 0) { atomicAdd(&hist[0], 1); atomicAdd(&hist[W_], 1); }
  __syncthreads();

  // 4) inclusive scan of histogram
  for (int i = t; i <= W_; i += 256) sa[i] = (double)hist[i];
  __syncthreads();
  scan_fast<W_ + 1>(sa, t, wtmp);
  for (int i = t; i <= W_; i += 256) hist[i] = (int)(sa[i] + 0.5);
  __syncthreads();

  // 5) sorted cuts: cuts[k] = min v with hist_incl[v] > k
  for (int k = t; k < NCUTS_; k += 256) {
    int lo = 0, hi = W_;
    while (lo < hi) { int mid = (lo + hi) >> 1; if (hist[mid] > k) hi = mid; else lo = mid + 1; }
    cuts[k] = lo;
  }
  __syncthreads();

  // 6) permuted lengths + cumulative sum
  for (int k = t; k < NSEG_; k += 256) { int p = perm.p[k]; pl[k] = cuts[p + 1] - cuts[p]; }
  __syncthreads();
  for (int k = t; k < NSEG_; k += 256) sa[k] = (double)pl[k];
  __syncthreads();
  scan_fast<NSEG_>(sa, t, wtmp);
  for (int k = t; k < NSEG_; k += 256) cum[k] = (int)(sa[k] + 0.5);
  __syncthreads();

  // 7) fill src
  for (int k = t; k < NSEG_; k += 256) {
    int L = pl[k];
    if (L > 0) {
      int base = cum[k] - L;
      int s0 = cuts[perm.p[k]];
      for (int j = 0; j < L; ++j) ssrc[base + j] = s0 + j;
    }
  }
  __syncthreads();
  for (int p = t; p < W_; p += 256) src[p] = ssrc[p];
}

// ---------------- pass 3: gather — R10 best config (4-row dbuf tiles, int4 idx) ----------------
__global__ __launch_bounds__(256) void k_gather(const float* __restrict__ img,
                                                float* __restrict__ out,
                                                const int* __restrict__ src,
                                                int ntile4, int rows) {
  __shared__ float buf[2][TFLT_];          // 2 x 11040 B
  __shared__ __align__(16) int ss[2 * W_]; // row-resolved source idx (1380)
  const int t = threadIdx.x;
  for (int i = t; i < W_; i += 256) {
    int s = src[i];
    ss[i] = s;
    ss[i + W_] = s + W_;
  }

  auto stage = [&](float* bp, int g) {
    const v4f_* in4 = (const v4f_*)(img + (size_t)g * TFLT_); // 16B aligned
    v4f_* t4 = (v4f_*)bp;
    for (int i = t; i < TF4_; i += 256) t4[i] = in4[i];
  };

  int g = blockIdx.x;
  int phase = 0;
  if (g < ntile4) stage(buf[0], g);
  for (; g < ntile4; g += gridDim.x) {
    __syncthreads(); // buf[phase] staged; prior reads of buf[phase^1] done
    const int gn = g + gridDim.x;
    if (gn < ntile4) stage(buf[phase ^ 1], gn); // prefetch next tile
    const float* bp = buf[phase];
    v4f_* o4 = (v4f_*)(out + (size_t)g * TFLT_);
    for (int q = t; q < TF4_; q += 256) {
      const int f = 4 * q;                       // quads never cross the 1380 boundary
      const int hb = (f >= 2 * W_) ? 2 * W_ : 0; // 2-row half base
      const float* hbuf = bp + hb;
      const v4i_ iv = *(const v4i_*)&ss[f - hb]; // one ds_read_b128
      v4f_ v;
      v[0] = hbuf[iv[0]];
      v[1] = hbuf[iv[1]];
      v[2] = hbuf[iv[2]];
      v[3] = hbuf[iv[3]];
      __builtin_nontemporal_store(v, &o4[q]);
    }
    phase ^= 1;
  }
  // tail rows (rows % 4), scalar — not hit for rows=65536
  const int tail0 = ntile4 * TR4_;
  if (tail0 < rows && blockIdx.x == 0) {
    __syncthreads();
    for (int r = tail0; r < rows; ++r) {
      const float* in = img + (size_t)r * W_;
      float* o = out + (size_t)r * W_;
      for (int p = t; p < W_; p += 256) o[p] = in[ss[p]];
    }
  }
}

extern "C" void kernel_launch(void* const* d_in, const int* in_sizes, int n_in,
                              void* d_out, int out_size, void* d_ws, size_t ws_size,
                              hipStream_t stream) {
  const float* img = (const float*)d_in[0];
  float* out = (float*)d_out;
  const int rows = in_sizes[0] / W_; // 32*2048 = 65536

  // ws layout: col f64[690] @0 | src i32[690] @5632 | partial @8704:
  //   [nblk][1380] f64 + [690] f64 tail
  char* ws = (char*)d_ws;
  double* col = (double*)ws;
  int* src = (int*)(ws + 5632);
  double* partial = (double*)(ws + 8704);
  size_t avail = (ws_size > 8704 + 5520) ? ws_size - 8704 - 5520 : 0;
  int nblk = (int)std::min<size_t>(2048, avail / (GFLT_ * sizeof(double)));
  if (nblk < 1) nblk = 1;
  const int nwin = rows / GR_;   // 32768 full 2-row windows
  const int ntile4 = rows / TR4_;

  PermArg pa;
  compute_perm(pa.p); // host, input-independent, deterministic

  k_colsum<<<nblk, 256, 0, stream>>>(img, partial, nwin, rows);
  k_colreduce<<<W_, 64, 0, stream>>>(partial, col, nblk);
  k_map<<<1, 256, 0, stream>>>(col, src, pa);
  k_gather<<<1280, 256, 0, stream>>>(img, out, src, ntile4, rows);
}

// Round 15
// 110.406 us; speedup vs baseline: 1.2123x; 1.1958x over previous
//
#include <hip/hip_runtime.h>
#include <algorithm>
#include <cstdint>

// PRNG: partitionable threefry, 32-bit combine = o0 ^ o1  [VERIFIED R4: absmax=0]
// Ledger: R8 gl2lds NEUTRAL; R9 fused-map -9us (device fence); R11 occupancy
// NEUTRAL; R12 T14 split NEUTRAL; R13/R14 reg-accum colsum -16us (falsified MLP
// theory -> suspect reduction path). R15: R10 structure + coalesced 2-stage
// colreduce (88 blocks, 64-consecutive-col waves; stage2 folded into k_map).

constexpr int W_ = 690;
constexpr int NSEG_ = 2 * W_ + 1;   // 1381 segments
constexpr int NCUTS_ = 2 * W_ + 2;  // 1382 cut points
constexpr int TR4_ = 4;             // rows per tile (colsum / gather)
constexpr int TFLT_ = TR4_ * W_;    // 2760 floats = 11040 B (16B-aligned tiles)
constexpr int TF4_ = TFLT_ / 4;     // 690 float4 per tile

typedef float v4f_ __attribute__((ext_vector_type(4)));
typedef int v4i_ __attribute__((ext_vector_type(4)));

struct PermArg { unsigned short p[NSEG_]; }; // 2762 B kernarg, values < 1381

// ---------------- host-side threefry2x32 (exact JAX semantics) ----------------
static inline uint32_t rotl32_(uint32_t x, int d) { return (x << d) | (x >> (32 - d)); }

static void tf2x32(uint32_t k0, uint32_t k1, uint32_t x0, uint32_t x1,
                   uint32_t& o0, uint32_t& o1) {
  const uint32_t ks2 = k0 ^ k1 ^ 0x1BD11BDAu;
  x0 += k0; x1 += k1;
  const int RA[4] = {13, 15, 26, 6}, RB[4] = {17, 29, 16, 24};
#define FOUR_(R) for (int i_ = 0; i_ < 4; ++i_) { x0 += x1; x1 = rotl32_(x1, R[i_]); x1 ^= x0; }
  FOUR_(RA) x0 += k1;  x1 += ks2 + 1u;
  FOUR_(RB) x0 += ks2; x1 += k0 + 2u;
  FOUR_(RA) x0 += k0;  x1 += k1 + 3u;
  FOUR_(RB) x0 += k1;  x1 += ks2 + 4u;
  FOUR_(RA) x0 += ks2; x1 += k0 + 5u;
#undef FOUR_
  o0 = x0; o1 = x1;
}

// perm = argsort(uniform(key(42), (1381,))) — pure function of constants.
static void compute_perm(unsigned short* perm) {
  uint32_t uk[NSEG_];
  for (int i = 0; i < NSEG_; ++i) {
    uint32_t o0, o1;
    tf2x32(0u, 42u, 0u, (uint32_t)i, o0, o1); // u64 count i: hi=0 -> x0, lo=i -> x1
    uk[i] = (o0 ^ o1) >> 9; // partitionable bit_width==32: bits1 ^ bits2
  }
  int idx[NSEG_];
  for (int i = 0; i < NSEG_; ++i) idx[i] = i;
  std::stable_sort(idx, idx + NSEG_, [&](int a, int b) { return uk[a] < uk[b]; });
  for (int k = 0; k < NSEG_; ++k) perm[k] = (unsigned short)idx[k];
}

// ---------------- pass 1: double-buffered reg-staged LDS colsum (R10 verbatim) ----------------
__global__ __launch_bounds__(256) void k_colsum(const float* __restrict__ img,
                                                double* __restrict__ partial,
                                                int ntiles, int rows) {
  __shared__ float buf[2][TFLT_]; // 2 x 11040 B
  const int t = threadIdx.x;
  double a0 = 0.0, a1 = 0.0, a2 = 0.0;

  auto stage = [&](float* bp, int g) {
    const int nr = min(TR4_, rows - g * TR4_);
    if (nr == TR4_) {
      const v4f_* b4 = (const v4f_*)(img + (size_t)g * TFLT_); // 11040B*g: 16B aligned
      v4f_* t4 = (v4f_*)bp;
      for (int i = t; i < TF4_; i += 256) t4[i] = b4[i];
    } else {
      const int nflt = nr * W_;
      const float* b = img + (size_t)g * TFLT_;
      for (int i = t; i < nflt; i += 256) bp[i] = b[i];
    }
  };

  int g = blockIdx.x;
  int phase = 0;
  if (g < ntiles) stage(buf[0], g);
  for (; g < ntiles; g += gridDim.x) {
    __syncthreads(); // buf[phase] staged; prev accumulate of buf[phase^1] done
    const int gn = g + gridDim.x;
    if (gn < ntiles) stage(buf[phase ^ 1], gn); // prefetch next while we accumulate
    const int nr = min(TR4_, rows - g * TR4_);
    const float* bp = buf[phase];
    for (int r = 0; r < nr; ++r) {
      const float* row = bp + r * W_;
      a0 += (double)row[t];
      a1 += (double)row[t + 256];          // t+256 <= 511 < 690 always
      if (t + 512 < W_) a2 += (double)row[t + 512];
    }
    phase ^= 1;
  }
  double* o = partial + (size_t)blockIdx.x * W_;
  o[t] = a0;
  o[t + 256] = a1;
  if (t + 512 < W_) o[t + 512] = a2;
}

// ---------------- pass 1b: coalesced 2-stage reduction ----------------
// Grid 88 = 11 col-chunks x 8 b-chunks. Wave reads 64 CONSECUTIVE f64 per step
// (one 512B burst, each cache line fetched once, no cross-XCD duplication).
// Output stage2[8][690]; k_map folds the 8 rows (fixed order -> deterministic).
__global__ __launch_bounds__(256) void k_colreduce(const double* __restrict__ partial,
                                                   double* __restrict__ stage2, int nblk) {
  const int j = blockIdx.x >> 3;   // col chunk 0..10
  const int k = blockIdx.x & 7;    // b chunk 0..7
  const int t = threadIdx.x;
  const int c = j * 64 + (t & 63); // column
  const int wv = t >> 6;           // wave 0..3
  const bool ok = (c < W_);
  __shared__ double red[4][64];

  const int nsub = (nblk + 31) / 32;
  const int b0 = (k * 4 + wv) * nsub;
  const int b1 = min(b0 + nsub, nblk);
  double s0 = 0.0, s1 = 0.0, s2 = 0.0, s3 = 0.0;
  int b = b0;
  if (ok) {
    for (; b + 3 < b1; b += 4) { // 4 independent chains -> 4 loads in flight
      const double* p = partial + (size_t)b * W_ + c;
      s0 += p[0];
      s1 += p[(size_t)1 * W_];
      s2 += p[(size_t)2 * W_];
      s3 += p[(size_t)3 * W_];
    }
    for (; b < b1; ++b) s0 += partial[(size_t)b * W_ + c];
  }
  red[wv][t & 63] = (s0 + s1) + (s2 + s3);
  __syncthreads();
  if (wv == 0) {
    const int l = t & 63;
    const double tot = (red[0][l] + red[1][l]) + (red[2][l] + red[3][l]);
    if (ok) stage2[(size_t)k * W_ + c] = tot;
  }
}

// ---------------- hierarchical inclusive scan: 2 barriers, deterministic ----------------
template <int N>
__device__ inline void scan_fast(double* sa, int t, double* wtmp) {
  constexpr int C = (N + 255) / 256;
  double loc[C];
  const int base = t * C;
  double run = 0.0;
#pragma unroll
  for (int j = 0; j < C; ++j) {
    const int i = base + j;
    const double v = (i < N) ? sa[i] : 0.0;
    run += v;
    loc[j] = run;
  }
  const int lane = t & 63, wid = t >> 6;
  double x = run;
#pragma unroll
  for (int off = 1; off < 64; off <<= 1) {
    const double y = __shfl_up(x, off);
    if (lane >= off) x += y;
  }
  if (lane == 63) wtmp[wid] = x;
  __syncthreads(); // all sa reads done; wave totals visible
  double excl = x - run;
  for (int k = 0; k < wid; ++k) excl += wtmp[k];
#pragma unroll
  for (int j = 0; j < C; ++j) {
    const int i = base + j;
    if (i < N) sa[i] = excl + loc[j];
  }
  __syncthreads();
}

// ---------------- pass 2: mapping pipeline (stage2 fold + scans), one block ----------------
__global__ __launch_bounds__(256) void k_map(const double* __restrict__ stage2,
                                             int* __restrict__ src, PermArg perm) {
  __shared__ double sa[NCUTS_];
  __shared__ double wtmp[4];
  __shared__ float ex[W_ + 1];
  __shared__ unsigned char mm[W_];
  __shared__ int hist[W_ + 1];
  __shared__ int cuts[NCUTS_];
  __shared__ int pl[NSEG_], cum[NSEG_], ssrc[W_];
  const int t = threadIdx.x;

  // 0+1) fold stage2 (fixed k order) then prefix-scan; cast to f32 like reference cs
  for (int i = t; i < W_; i += 256) {
    double s = 0.0;
#pragma unroll
    for (int k = 0; k < 8; ++k) s += stage2[(size_t)k * W_ + i];
    sa[i] = s;
  }
  __syncthreads();
  scan_fast<W_>(sa, t, wtmp);
  for (int i = t; i <= W_; i += 256) ex[i] = (i == 0) ? 0.0f : (float)sa[i - 1];
  __syncthreads();

  // 2) windowed mean >= global mean mask
  const float gmean = ex[W_] / 45219840.0f; // n_bc*W = 65536*690
  for (int w = t; w < W_; w += 256) {
    int e = (w + 4 < W_) ? w + 4 : W_;
    float wsum = ex[e] - ex[w];
    float wmean = wsum / ((float)(e - w) * 65536.0f);
    mm[w] = (wmean >= gmean) ? 1 : 0;
  }
  for (int i = t; i <= W_; i += 256) hist[i] = 0;
  __syncthreads();

  // 3) counting-sort histogram of cut values
  for (int w = t; w < W_; w += 256) {
    bool cur = mm[w] != 0;
    bool prv = (w > 0) && (mm[w - 1] != 0);
    bool nxt = (w < W_ - 1) && (mm[w + 1] != 0);
    int sv = (cur && !prv) ? w : W_;
    int lv = (cur && !nxt) ? w : W_;
    atomicAdd(&hist[sv], 1);
    atomicAdd(&hist[lv], 1);
  }
  if (t == 0) { atomicAdd(&hist[0], 1); atomicAdd(&hist[W_], 1); }
  __syncthreads();

  // 4) inclusive scan of histogram
  for (int i = t; i <= W_; i += 256) sa[i] = (double)hist[i];
  __syncthreads();
  scan_fast<W_ + 1>(sa, t, wtmp);
  for (int i = t; i <= W_; i += 256) hist[i] = (int)(sa[i] + 0.5);
  __syncthreads();

  // 5) sorted cuts: cuts[k] = min v with hist_incl[v] > k
  for (int k = t; k < NCUTS_; k += 256) {
    int lo = 0, hi = W_;
    while (lo < hi) { int mid = (lo + hi) >> 1; if (hist[mid] > k) hi = mid; else lo = mid + 1; }
    cuts[k] = lo;
  }
  __syncthreads();

  // 6) permuted lengths + cumulative sum
  for (int k = t; k < NSEG_; k += 256) { int p = perm.p[k]; pl[k] = cuts[p + 1] - cuts[p]; }
  __syncthreads();
  for (int k = t; k < NSEG_; k += 256) sa[k] = (double)pl[k];
  __syncthreads();
  scan_fast<NSEG_>(sa, t, wtmp);
  for (int k = t; k < NSEG_; k += 256) cum[k] = (int)(sa[k] + 0.5);
  __syncthreads();

  // 7) fill src
  for (int k = t; k < NSEG_; k += 256) {
    int L = pl[k];
    if (L > 0) {
      int base = cum[k] - L;
      int s0 = cuts[perm.p[k]];
      for (int j = 0; j < L; ++j) ssrc[base + j] = s0 + j;
    }
  }
  __syncthreads();
  for (int p = t; p < W_; p += 256) src[p] = ssrc[p];
}

// ---------------- pass 3: double-buffered reg-staged LDS gather (R10 verbatim) ----------------
__global__ __launch_bounds__(256) void k_gather(const float* __restrict__ img,
                                                float* __restrict__ out,
                                                const int* __restrict__ src,
                                                int ntile4, int rows) {
  __shared__ float buf[2][TFLT_];          // 2 x 11040 B
  __shared__ __align__(16) int ss[2 * W_]; // row-resolved source idx (1380)
  const int t = threadIdx.x;
  for (int i = t; i < W_; i += 256) {
    int s = src[i];
    ss[i] = s;
    ss[i + W_] = s + W_;
  }

  auto stage = [&](float* bp, int g) {
    const v4f_* in4 = (const v4f_*)(img + (size_t)g * TFLT_); // 16B aligned
    v4f_* t4 = (v4f_*)bp;
    for (int i = t; i < TF4_; i += 256) t4[i] = in4[i];
  };

  int g = blockIdx.x;
  int phase = 0;
  if (g < ntile4) stage(buf[0], g);
  for (; g < ntile4; g += gridDim.x) {
    __syncthreads(); // buf[phase] staged; prior reads of buf[phase^1] done
    const int gn = g + gridDim.x;
    if (gn < ntile4) stage(buf[phase ^ 1], gn); // prefetch next tile
    const float* bp = buf[phase];
    v4f_* o4 = (v4f_*)(out + (size_t)g * TFLT_);
    for (int q = t; q < TF4_; q += 256) {
      const int f = 4 * q;                       // quads never cross the 1380 boundary
      const int hb = (f >= 2 * W_) ? 2 * W_ : 0; // 2-row half base
      const float* hbuf = bp + hb;
      const v4i_ iv = *(const v4i_*)&ss[f - hb]; // one ds_read_b128
      v4f_ v;
      v[0] = hbuf[iv[0]];
      v[1] = hbuf[iv[1]];
      v[2] = hbuf[iv[2]];
      v[3] = hbuf[iv[3]];
      __builtin_nontemporal_store(v, &o4[q]);
    }
    phase ^= 1;
  }
  // tail rows (rows % 4), scalar — not hit for rows=65536
  const int tail0 = ntile4 * TR4_;
  if (tail0 < rows && blockIdx.x == 0) {
    __syncthreads();
    for (int r = tail0; r < rows; ++r) {
      const float* in = img + (size_t)r * W_;
      float* o = out + (size_t)r * W_;
      for (int p = t; p < W_; p += 256) o[p] = in[ss[p]];
    }
  }
}

extern "C" void kernel_launch(void* const* d_in, const int* in_sizes, int n_in,
                              void* d_out, int out_size, void* d_ws, size_t ws_size,
                              hipStream_t stream) {
  const float* img = (const float*)d_in[0];
  float* out = (float*)d_out;
  const int rows = in_sizes[0] / W_; // 32*2048 = 65536

  // ws layout: stage2 f64[8*690] @0 (44160B) | src i32[690] @44160 | partial @47104
  char* ws = (char*)d_ws;
  double* stage2 = (double*)ws;
  int* src = (int*)(ws + 44160);
  double* partial = (double*)(ws + 47104);
  size_t avail = (ws_size > 47104) ? ws_size - 47104 : 0;
  int nblk = (int)std::min<size_t>(1792, avail / (W_ * sizeof(double)));
  if (nblk < 1) nblk = 1;
  const int ntiles = (rows + TR4_ - 1) / TR4_;
  const int ntile4 = rows / TR4_;

  PermArg pa;
  compute_perm(pa.p); // host, input-independent, deterministic

  k_colsum<<<nblk, 256, 0, stream>>>(img, partial, ntiles, rows);
  k_colreduce<<<88, 256, 0, stream>>>(partial, stage2, nblk);
  k_map<<<1, 256, 0, stream>>>(stage2, src, pa);
  k_gather<<<1280, 256, 0, stream>>>(img, out, src, ntile4, rows);
}